// Round 11
// baseline (345.321 us; speedup 1.0000x reference)
//
#include <hip/hip_runtime.h>

// B=8, N=2048, C=512. Flash attention + fp16 MFMA pipeline.
// attn r11: KVBLK=32 (two 16-key halves per iteration, ONE barrier per 32
// keys -> 32 iterations, testing the per-iteration latency-floor hypothesis).
// 512-thread blocks (8 waves share staging), split-K 2x1024, dbuf.
// G tile [512][32] with 16B-chunk XOR swizzle (gload16-compatible both-sides)
// -> PV b64 reads at service minimum. K XOR-swizzled as before.
// combine fused into final_gemm.
// ws: [0]=xb->OA [1]=h [2]=l [3]=gT [4]=OB [5]=Wt(2MB)+ml(256KB)

typedef __attribute__((ext_vector_type(4))) float f32x4;
typedef __attribute__((ext_vector_type(8))) short s16x8;      // fp16 bit-patterns
typedef __attribute__((ext_vector_type(4))) short s16x4;
typedef __attribute__((ext_vector_type(8))) _Float16 f16x8;   // MFMA operands
typedef __attribute__((ext_vector_type(4))) _Float16 f16x4;
typedef __attribute__((ext_vector_type(2))) unsigned u32x2;

typedef unsigned int u32;
typedef __attribute__((address_space(1))) const u32 gu32;
typedef __attribute__((address_space(3))) u32 lu32;

__device__ __forceinline__ void gload16(const short* g, short* l) {
  __builtin_amdgcn_global_load_lds((gu32*)g, (lu32*)l, 16, 0, 0);
}

__device__ __forceinline__ short f2h(float f) {
  _Float16 h = (_Float16)f;
  return __builtin_bit_cast(short, h);
}

__device__ __forceinline__ unsigned pk2h(float a, float b) {
  return __builtin_bit_cast(unsigned, __builtin_amdgcn_cvt_pkrtz(a, b));
}

#define MFMA(a, b, c) __builtin_amdgcn_mfma_f32_16x16x32_f16(a, b, c, 0, 0, 0)
#define MFMA16(a, b, c) __builtin_amdgcn_mfma_f32_16x16x16f16(a, b, c, 0, 0, 0)

// ---------------- conversion kernels ----------------

__global__ __launch_bounds__(256) void conv_x_kernel(const float* __restrict__ x,
                                                     short* __restrict__ xb) {
  int i = blockIdx.x * 256 + threadIdx.x;
  const float4* xv = (const float4*)x;
  float4 a = xv[2 * i], b = xv[2 * i + 1];
  s16x8 o;
  o[0] = f2h(a.x); o[1] = f2h(a.y); o[2] = f2h(a.z); o[3] = f2h(a.w);
  o[4] = f2h(b.x); o[5] = f2h(b.y); o[6] = f2h(b.z); o[7] = f2h(b.w);
  ((s16x8*)xb)[i] = o;
}

__global__ __launch_bounds__(256) void conv_w_kernel(const float* __restrict__ Wh,
                                                     const float* __restrict__ Wl,
                                                     const float* __restrict__ Wg,
                                                     const float* __restrict__ Wm,
                                                     short* __restrict__ Wt) {
  int idx = blockIdx.x * 256 + threadIdx.x;
  int k = idx & 511, n = (idx >> 9) & 511, w = idx >> 18;
  const float* W = (w == 0) ? Wh : (w == 1) ? Wl : (w == 2) ? Wg : Wm;
  Wt[idx] = f2h(W[k * 512 + n]);
}

// ---------------- fused 3-way MLP GEMM ----------------

__global__ __launch_bounds__(256) void mlp3_kernel(const short* __restrict__ A,
                                                   const short* __restrict__ Wt_all,
                                                   const float* __restrict__ bh,
                                                   const float* __restrict__ bl,
                                                   const float* __restrict__ bg,
                                                   short* __restrict__ h,
                                                   short* __restrict__ l,
                                                   short* __restrict__ gT) {
  int z = blockIdx.z;
  const short* Wt = Wt_all + z * 262144;
  const float* bias = (z == 0) ? bh : (z == 1) ? bl : bg;

  __shared__ __align__(16) short lds_a[128 * 40];
  __shared__ __align__(16) short lds_b[128 * 40];
  int tid = threadIdx.x, lane = tid & 63, w = tid >> 6;
  int wm = w >> 1, wn = w & 1;
  int bm = blockIdx.x * 128, bn = blockIdx.y * 128;

  f32x4 acc[4][4];
#pragma unroll
  for (int mi = 0; mi < 4; ++mi)
#pragma unroll
    for (int ni = 0; ni < 4; ++ni) acc[mi][ni] = (f32x4){0.f, 0.f, 0.f, 0.f};

  for (int k0 = 0; k0 < 512; k0 += 32) {
#pragma unroll
    for (int it = 0; it < 2; ++it) {
      int chunk = tid + it * 256;
      int row = chunk >> 2, c8 = (chunk & 3) * 8;
      *(s16x8*)&lds_a[row * 40 + c8] =
          *(const s16x8*)&A[(size_t)(bm + row) * 512 + k0 + c8];
      *(s16x8*)&lds_b[row * 40 + c8] =
          *(const s16x8*)&Wt[(bn + row) * 512 + k0 + c8];
    }
    __syncthreads();
    f16x8 af[4], bfr[4];
#pragma unroll
    for (int mi = 0; mi < 4; ++mi)
      af[mi] = *(const f16x8*)&lds_a[(wm * 64 + mi * 16 + (lane & 15)) * 40 +
                                     (lane >> 4) * 8];
#pragma unroll
    for (int ni = 0; ni < 4; ++ni)
      bfr[ni] = *(const f16x8*)&lds_b[(wn * 64 + ni * 16 + (lane & 15)) * 40 +
                                      (lane >> 4) * 8];
#pragma unroll
    for (int mi = 0; mi < 4; ++mi)
#pragma unroll
      for (int ni = 0; ni < 4; ++ni) acc[mi][ni] = MFMA(af[mi], bfr[ni], acc[mi][ni]);
    __syncthreads();
  }

#pragma unroll
  for (int mi = 0; mi < 4; ++mi)
#pragma unroll
    for (int ni = 0; ni < 4; ++ni) {
      int col = bn + wn * 64 + ni * 16 + (lane & 15);
      float bv = bias[col];
#pragma unroll
      for (int r = 0; r < 4; ++r) {
        int row = bm + wm * 64 + mi * 16 + (lane >> 4) * 4 + r;
        float v = fmaxf(acc[mi][ni][r] + bv, 0.0f);
        short o = f2h(v);
        if (z == 0) h[(size_t)row * 512 + col] = o;
        else if (z == 1) l[(size_t)row * 512 + col] = o;
        else {
          int bb = row >> 11, mm = row & 2047;
          gT[((size_t)bb * 512 + col) * 2048 + mm] = o;
        }
      }
    }
}

// ---------------- flash attention, split-K, KVBLK=32 ----------------
// 256 blocks x 512 threads (8 waves x 16 q). 32 iterations x 32 keys,
// one barrier per iteration. K[32][512] XOR-swizzled; G[512][32] chunk-swizzled.

__global__ __launch_bounds__(512, 2) void attn_split_kernel(
    const short* __restrict__ lmat, const short* __restrict__ hmat,
    const short* __restrict__ gT,
    short* __restrict__ OA, short* __restrict__ OB,
    float2* __restrict__ mlA, float2* __restrict__ mlB) {
  __shared__ __align__(16) short kbuf[2][16384];  // [32 keys][512]
  __shared__ __align__(16) short gbuf[2][16384];  // [512 c][32 keys]
  int tid = threadIdx.x, lane = tid & 63, w = tid >> 6;  // w in 0..7
  int b = blockIdx.x & 7;           // XCD j <- batch j
  int idx = blockIdx.x >> 3;        // 0..31
  int qt = idx >> 1, sp = idx & 1;
  int q0 = qt * 128 + w * 16;
  int keybase = sp * 1024;
  const short* lb = lmat + (size_t)b * 2048 * 512;
  const short* hb = hmat + (size_t)b * 2048 * 512;
  const short* gb = gT + (size_t)b * 512 * 2048;
  short* Op = sp ? OB : OA;
  float2* ml = sp ? mlB : mlA;

  int r0 = lane & 15, g = lane >> 4;

  // Q fragments (B-operand: lane&15 = query col, k-chunk g*8): 64 VGPR
  f16x8 qf[16];
  {
    int q = q0 + r0;
#pragma unroll
    for (int ks = 0; ks < 16; ++ks)
      qf[ks] = *(const f16x8*)&lb[(size_t)q * 512 + ks * 32 + g * 8];
  }
  f32x4 accO[32];  // O^T: query r0, d = nf*16 + g*4 + r
#pragma unroll
  for (int i = 0; i < 32; ++i) accO[i] = (f32x4){0.f, 0.f, 0.f, 0.f};
  float mrun = -3e38f, lsumL = 0.f;

  // staging: per wave per iteration: 4 K rows + 4 G row-groups (gload16 x8)
  auto stageK = [&](int buf, int t) {
    int key0 = keybase + t * 32;
    short* kd = &kbuf[buf][0];
#pragma unroll
    for (int j = 0; j < 4; ++j) {
      int wl = w * 4 + j;  // key row 0..31
      gload16(hb + (size_t)(key0 + wl) * 512 + (((lane * 16) ^ ((wl & 7) << 4)) >> 1),
              kd + wl * 512);
    }
  };
  // G: rows of 64B = 4 chunks of 16B; phys chunk = logical ^ (c&3).
  auto stageG = [&](int buf, int t) {
    int key0 = keybase + t * 32;
    short* gd = &gbuf[buf][0];
#pragma unroll
    for (int j = 0; j < 4; ++j) {
      int wl = w * 4 + j;               // 0..31, each covers 16 c-rows
      int c = wl * 16 + (lane >> 2);    // c row 0..511
      int chunk = (lane & 3) ^ ((lane >> 2) & 3);
      gload16(gb + (size_t)c * 2048 + key0 + chunk * 8, gd + wl * 512);
    }
  };
  auto QK = [&](int buf, f32x4& o0, f32x4& o1) {
    const short* kb = &kbuf[buf][0];
#pragma unroll
    for (int ks = 0; ks < 16; ++ks) {
      f16x8 k0f = *(const f16x8*)&kb[(r0 * 512 + ks * 32 + g * 8) ^ ((r0 & 7) << 3)];
      o0 = MFMA(k0f, qf[ks], o0);
      f16x8 k1f = *(const f16x8*)&kb[((r0 + 16) * 512 + ks * 32 + g * 8) ^ ((r0 & 7) << 3)];
      o1 = MFMA(k1f, qf[ks], o1);
    }
  };

  stageK(0, 0); stageG(0, 0); stageK(1, 1);
  __syncthreads();
  f32x4 sc0 = {0.f, 0.f, 0.f, 0.f}, sc1 = {0.f, 0.f, 0.f, 0.f};
  QK(0, sc0, sc1);
  __syncthreads();

  // hoisted swizzled PV offsets (row&3 == r0&3, loop-invariant)
  int goff0 = r0 * 32 + ((((g >> 1) ^ (r0 & 3)) << 3) | ((g & 1) << 2));
  int goff1 = r0 * 32 + (((((g >> 1) | 2) ^ (r0 & 3)) << 3) | ((g & 1) << 2));

  for (int t = 0; t < 32; ++t) {
    if (t < 30) stageK(t & 1, t + 2);
    if (t < 31) stageG((t + 1) & 1, t + 1);

    f32x4 sn0 = {0.f, 0.f, 0.f, 0.f}, sn1 = {0.f, 0.f, 0.f, 0.f};
    if (t < 31) {
      __builtin_amdgcn_s_setprio(1);
      QK((t + 1) & 1, sn0, sn1);
      __builtin_amdgcn_s_setprio(0);
    }

    // ---- softmax(t): 8 scores/lane, lane-local + 2 shuffles ----
    float m2 = fmaxf(fmaxf(fmaxf(sc0[0], sc0[1]), fmaxf(sc0[2], sc0[3])),
                     fmaxf(fmaxf(sc1[0], sc1[1]), fmaxf(sc1[2], sc1[3])));
    m2 = fmaxf(m2, __shfl_xor(m2, 16));
    m2 = fmaxf(m2, __shfl_xor(m2, 32));
    bool ok = (m2 <= mrun + 8.0f);  // defer-max THR=8
    if (!__all((int)ok)) {
      float mnew = fmaxf(mrun, m2);
      float s = __expf(mrun - mnew);
      mrun = mnew;
      lsumL *= s;
#pragma unroll
      for (int nf = 0; nf < 32; ++nf) accO[nf] *= s;
    }
    float a0 = __expf(sc0[0] - mrun), a1 = __expf(sc0[1] - mrun);
    float a2 = __expf(sc0[2] - mrun), a3 = __expf(sc0[3] - mrun);
    float b0 = __expf(sc1[0] - mrun), b1 = __expf(sc1[1] - mrun);
    float b2 = __expf(sc1[2] - mrun), b3 = __expf(sc1[3] - mrun);
    lsumL += (a0 + a1) + (a2 + a3) + (b0 + b1) + (b2 + b3);

    // P-fragments per half: 16x16x16 B-operand k-slots == QK C rows.
    u32x2 pw0 = {pk2h(a0, a1), pk2h(a2, a3)};
    u32x2 pw1 = {pk2h(b0, b1), pk2h(b2, b3)};
    f16x4 pf0 = __builtin_bit_cast(f16x4, pw0);
    f16x4 pf1 = __builtin_bit_cast(f16x4, pw1);

    // ---- PV(t): both halves accumulate into accO ----
    const short* gp0 = &gbuf[t & 1][goff0];
    const short* gp1 = &gbuf[t & 1][goff1];
    __builtin_amdgcn_s_setprio(1);
#pragma unroll
    for (int nf = 0; nf < 32; ++nf) {
      f16x4 gf0 = *(const f16x4*)&gp0[nf * 512];
      accO[nf] = MFMA16(gf0, pf0, accO[nf]);
      f16x4 gf1 = *(const f16x4*)&gp1[nf * 512];
      accO[nf] = MFMA16(gf1, pf1, accO[nf]);
    }
    __builtin_amdgcn_s_setprio(0);

    __syncthreads();
    sc0 = sn0; sc1 = sn1;
  }

  // ---- epilogue: store normalized O (fp16) + (m, l) sidecar ----
  float ls = lsumL;
  ls += __shfl_xor(ls, 16);
  ls += __shfl_xor(ls, 32);
  float inv = 1.0f / ls;
  int q = q0 + r0;
#pragma unroll
  for (int nf = 0; nf < 32; ++nf) {
    s16x4 o;
    o[0] = f2h(accO[nf][0] * inv);
    o[1] = f2h(accO[nf][1] * inv);
    o[2] = f2h(accO[nf][2] * inv);
    o[3] = f2h(accO[nf][3] * inv);
    *(s16x4*)&Op[((size_t)b * 2048 + q) * 512 + nf * 16 + g * 4] = o;
  }
  if (g == 0) ml[(size_t)b * 2048 + q] = make_float2(mrun, ls);
}

// ---------------- fused combine + final GEMM ----------------

__global__ __launch_bounds__(256) void final_gemm_kernel(
    const short* __restrict__ OA, const short* __restrict__ OB,
    const float2* __restrict__ mlA, const float2* __restrict__ mlB,
    const float* __restrict__ x, const short* __restrict__ Wt,
    const float* __restrict__ bias, float* __restrict__ out) {
  __shared__ __align__(16) short lds_a[64 * 40];
  __shared__ __align__(16) short lds_b[512 * 40];
  int tid = threadIdx.x, lane = tid & 63, w = tid >> 6;
  int bm = blockIdx.x * 64;

  int arow = tid >> 2, ac8 = (tid & 3) * 8;
  int grow = bm + arow;
  float2 a2 = mlA[grow], b2 = mlB[grow];
  float ms = fmaxf(a2.x, b2.x);
  float wA = __expf(a2.x - ms) * a2.y;
  float wB = __expf(b2.x - ms) * b2.y;
  float winv = 1.0f / (wA + wB);
  wA *= winv; wB *= winv;

  f32x4 acc[32];
#pragma unroll
  for (int i = 0; i < 32; ++i) acc[i] = (f32x4){0.f, 0.f, 0.f, 0.f};

  for (int k0 = 0; k0 < 512; k0 += 32) {
    {
      size_t base = (size_t)grow * 512 + k0 + ac8;
      f16x8 oa = *(const f16x8*)&OA[base];
      f16x8 ob = *(const f16x8*)&OB[base];
      float4 x0 = *(const float4*)&x[base];
      float4 x1 = *(const float4*)&x[base + 4];
      s16x8 av;
      av[0] = f2h((float)oa[0] * wA + (float)ob[0] * wB + x0.x);
      av[1] = f2h((float)oa[1] * wA + (float)ob[1] * wB + x0.y);
      av[2] = f2h((float)oa[2] * wA + (float)ob[2] * wB + x0.z);
      av[3] = f2h((float)oa[3] * wA + (float)ob[3] * wB + x0.w);
      av[4] = f2h((float)oa[4] * wA + (float)ob[4] * wB + x1.x);
      av[5] = f2h((float)oa[5] * wA + (float)ob[5] * wB + x1.y);
      av[6] = f2h((float)oa[6] * wA + (float)ob[6] * wB + x1.z);
      av[7] = f2h((float)oa[7] * wA + (float)ob[7] * wB + x1.w);
      *(s16x8*)&lds_a[arow * 40 + ac8] = av;
    }
#pragma unroll
    for (int it = 0; it < 8; ++it) {
      int chunk = tid + it * 256;
      int row = chunk >> 2, c8 = (chunk & 3) * 8;
      *(s16x8*)&lds_b[row * 40 + c8] =
          *(const s16x8*)&Wt[(size_t)row * 512 + k0 + c8];
    }
    __syncthreads();
    f16x8 af = *(const f16x8*)&lds_a[(w * 16 + (lane & 15)) * 40 + (lane >> 4) * 8];
#pragma unroll
    for (int nf = 0; nf < 32; ++nf) {
      f16x8 bf = *(const f16x8*)&lds_b[(nf * 16 + (lane & 15)) * 40 + (lane >> 4) * 8];
      acc[nf] = MFMA(af, bf, acc[nf]);
    }
    __syncthreads();
  }

#pragma unroll
  for (int nf = 0; nf < 32; ++nf) {
    int col = nf * 16 + (lane & 15);
    float bv = bias[col];
#pragma unroll
    for (int r = 0; r < 4; ++r) {
      int row = bm + w * 16 + (lane >> 4) * 4 + r;
      out[(size_t)row * 512 + col] = fmaxf(acc[nf][r] + bv, 0.0f);
    }
  }
}

// ---------------- host launch ----------------

extern "C" void kernel_launch(void* const* d_in, const int* in_sizes, int n_in,
                              void* d_out, int out_size, void* d_ws, size_t ws_size,
                              hipStream_t stream) {
  const float* x  = (const float*)d_in[0];
  const float* Wh = (const float*)d_in[1];
  const float* bh = (const float*)d_in[2];
  const float* Wl = (const float*)d_in[3];
  const float* bl = (const float*)d_in[4];
  const float* Wg = (const float*)d_in[5];
  const float* bg = (const float*)d_in[6];
  const float* Wm = (const float*)d_in[7];
  const float* bm = (const float*)d_in[8];

  char* ws = (char*)d_ws;
  const size_t SZ = 16777216;
  short*  xb  = (short*)(ws + 0 * SZ);   // conv_x out; reused as OA by attn
  short*  h   = (short*)(ws + 1 * SZ);
  short*  l   = (short*)(ws + 2 * SZ);
  short*  gT  = (short*)(ws + 3 * SZ);
  short*  OB  = (short*)(ws + 4 * SZ);
  short*  Wt  = (short*)(ws + 5 * SZ);   // 2 MB
  float2* mlA = (float2*)(ws + 5 * SZ + 2097152);            // 128 KB
  float2* mlB = (float2*)(ws + 5 * SZ + 2097152 + 131072);   // 128 KB

  conv_x_kernel<<<4096, 256, 0, stream>>>(x, xb);
  conv_w_kernel<<<4096, 256, 0, stream>>>(Wh, Wl, Wg, Wm, Wt);
  mlp3_kernel<<<dim3(128, 4, 3), 256, 0, stream>>>(xb, Wt, bh, bl, bg, h, l, gT);
  attn_split_kernel<<<256, 512, 0, stream>>>(l, h, gT, xb, OB, mlA, mlB);
  final_gemm_kernel<<<256, 256, 0, stream>>>(xb, OB, mlA, mlB, x,
                                             Wt + 3 * 262144, bm, (float*)d_out);
}

// Round 12
// 235.277 us; speedup vs baseline: 1.4677x; 1.4677x over previous
//
#include <hip/hip_runtime.h>

// B=8, N=2048, C=512. Flash attention + fp16 MFMA pipeline.
// attn r12 (on r10 base): (1) G tile 16B-half XOR swizzle keyed on (c>>2)&1
// -> PV b64 reads 2-way (free); gload16-compatible both-sides. (2) counted
// vmcnt raw barriers: K triple-buffered (stage t+3), G double (t+1); issue
// G-then-K; s_waitcnt vmcnt(2) + s_barrier + sched_barrier(0) per iter
// (prefetch DMA survives the barrier; no more vmcnt(0) drain).
// split-K 2x1024, KVBLK=16, 512-thread blocks, 80KB LDS.
// ws: [0]=xb->OA [1]=h [2]=l [3]=gT [4]=OB [5]=Wt(2MB)+ml(256KB)

typedef __attribute__((ext_vector_type(4))) float f32x4;
typedef __attribute__((ext_vector_type(8))) short s16x8;      // fp16 bit-patterns
typedef __attribute__((ext_vector_type(4))) short s16x4;
typedef __attribute__((ext_vector_type(8))) _Float16 f16x8;   // MFMA operands
typedef __attribute__((ext_vector_type(4))) _Float16 f16x4;
typedef __attribute__((ext_vector_type(2))) unsigned u32x2;

typedef unsigned int u32;
typedef __attribute__((address_space(1))) const u32 gu32;
typedef __attribute__((address_space(3))) u32 lu32;

__device__ __forceinline__ void gload16(const short* g, short* l) {
  __builtin_amdgcn_global_load_lds((gu32*)g, (lu32*)l, 16, 0, 0);
}

__device__ __forceinline__ short f2h(float f) {
  _Float16 h = (_Float16)f;
  return __builtin_bit_cast(short, h);
}

__device__ __forceinline__ unsigned pk2h(float a, float b) {
  return __builtin_bit_cast(unsigned, __builtin_amdgcn_cvt_pkrtz(a, b));
}

#define MFMA(a, b, c) __builtin_amdgcn_mfma_f32_16x16x32_f16(a, b, c, 0, 0, 0)
#define MFMA16(a, b, c) __builtin_amdgcn_mfma_f32_16x16x16f16(a, b, c, 0, 0, 0)

// counted-vmcnt barrier: keep newest 2 vmem ops (own K(t+3)) in flight
#define BAR_KEEP2()                                          \
  do {                                                       \
    asm volatile("s_waitcnt vmcnt(2)" ::: "memory");         \
    __builtin_amdgcn_s_barrier();                            \
    __builtin_amdgcn_sched_barrier(0);                       \
  } while (0)
#define BAR_ALL()                                            \
  do {                                                       \
    asm volatile("s_waitcnt vmcnt(0)" ::: "memory");         \
    __builtin_amdgcn_s_barrier();                            \
    __builtin_amdgcn_sched_barrier(0);                       \
  } while (0)

// ---------------- conversion kernels ----------------

__global__ __launch_bounds__(256) void conv_x_kernel(const float* __restrict__ x,
                                                     short* __restrict__ xb) {
  int i = blockIdx.x * 256 + threadIdx.x;
  const float4* xv = (const float4*)x;
  float4 a = xv[2 * i], b = xv[2 * i + 1];
  s16x8 o;
  o[0] = f2h(a.x); o[1] = f2h(a.y); o[2] = f2h(a.z); o[3] = f2h(a.w);
  o[4] = f2h(b.x); o[5] = f2h(b.y); o[6] = f2h(b.z); o[7] = f2h(b.w);
  ((s16x8*)xb)[i] = o;
}

__global__ __launch_bounds__(256) void conv_w_kernel(const float* __restrict__ Wh,
                                                     const float* __restrict__ Wl,
                                                     const float* __restrict__ Wg,
                                                     const float* __restrict__ Wm,
                                                     short* __restrict__ Wt) {
  int idx = blockIdx.x * 256 + threadIdx.x;
  int k = idx & 511, n = (idx >> 9) & 511, w = idx >> 18;
  const float* W = (w == 0) ? Wh : (w == 1) ? Wl : (w == 2) ? Wg : Wm;
  Wt[idx] = f2h(W[k * 512 + n]);
}

// ---------------- fused 3-way MLP GEMM ----------------

__global__ __launch_bounds__(256) void mlp3_kernel(const short* __restrict__ A,
                                                   const short* __restrict__ Wt_all,
                                                   const float* __restrict__ bh,
                                                   const float* __restrict__ bl,
                                                   const float* __restrict__ bg,
                                                   short* __restrict__ h,
                                                   short* __restrict__ l,
                                                   short* __restrict__ gT) {
  int z = blockIdx.z;
  const short* Wt = Wt_all + z * 262144;
  const float* bias = (z == 0) ? bh : (z == 1) ? bl : bg;

  __shared__ __align__(16) short lds_a[128 * 40];
  __shared__ __align__(16) short lds_b[128 * 40];
  int tid = threadIdx.x, lane = tid & 63, w = tid >> 6;
  int wm = w >> 1, wn = w & 1;
  int bm = blockIdx.x * 128, bn = blockIdx.y * 128;

  f32x4 acc[4][4];
#pragma unroll
  for (int mi = 0; mi < 4; ++mi)
#pragma unroll
    for (int ni = 0; ni < 4; ++ni) acc[mi][ni] = (f32x4){0.f, 0.f, 0.f, 0.f};

  for (int k0 = 0; k0 < 512; k0 += 32) {
#pragma unroll
    for (int it = 0; it < 2; ++it) {
      int chunk = tid + it * 256;
      int row = chunk >> 2, c8 = (chunk & 3) * 8;
      *(s16x8*)&lds_a[row * 40 + c8] =
          *(const s16x8*)&A[(size_t)(bm + row) * 512 + k0 + c8];
      *(s16x8*)&lds_b[row * 40 + c8] =
          *(const s16x8*)&Wt[(bn + row) * 512 + k0 + c8];
    }
    __syncthreads();
    f16x8 af[4], bfr[4];
#pragma unroll
    for (int mi = 0; mi < 4; ++mi)
      af[mi] = *(const f16x8*)&lds_a[(wm * 64 + mi * 16 + (lane & 15)) * 40 +
                                     (lane >> 4) * 8];
#pragma unroll
    for (int ni = 0; ni < 4; ++ni)
      bfr[ni] = *(const f16x8*)&lds_b[(wn * 64 + ni * 16 + (lane & 15)) * 40 +
                                      (lane >> 4) * 8];
#pragma unroll
    for (int mi = 0; mi < 4; ++mi)
#pragma unroll
      for (int ni = 0; ni < 4; ++ni) acc[mi][ni] = MFMA(af[mi], bfr[ni], acc[mi][ni]);
    __syncthreads();
  }

#pragma unroll
  for (int mi = 0; mi < 4; ++mi)
#pragma unroll
    for (int ni = 0; ni < 4; ++ni) {
      int col = bn + wn * 64 + ni * 16 + (lane & 15);
      float bv = bias[col];
#pragma unroll
      for (int r = 0; r < 4; ++r) {
        int row = bm + wm * 64 + mi * 16 + (lane >> 4) * 4 + r;
        float v = fmaxf(acc[mi][ni][r] + bv, 0.0f);
        short o = f2h(v);
        if (z == 0) h[(size_t)row * 512 + col] = o;
        else if (z == 1) l[(size_t)row * 512 + col] = o;
        else {
          int bb = row >> 11, mm = row & 2047;
          gT[((size_t)bb * 512 + col) * 2048 + mm] = o;
        }
      }
    }
}

// ---------------- flash attention, split-K ----------------
// 256 blocks x 512 threads (8 waves x 16 q). 64 tiles of 16 keys per block.
// K triple-buffered [16][512] XOR-swizzled; G double [512][16] half-swizzled.

__global__ __launch_bounds__(512, 1) void attn_split_kernel(
    const short* __restrict__ lmat, const short* __restrict__ hmat,
    const short* __restrict__ gT,
    short* __restrict__ OA, short* __restrict__ OB,
    float2* __restrict__ mlA, float2* __restrict__ mlB) {
  __shared__ __align__(16) short kbuf[3][8192];  // 48KB
  __shared__ __align__(16) short gbuf[2][8192];  // 32KB
  int tid = threadIdx.x, lane = tid & 63, w = tid >> 6;  // w in 0..7
  int b = blockIdx.x & 7;           // XCD j <- batch j
  int idx = blockIdx.x >> 3;        // 0..31
  int qt = idx >> 1, sp = idx & 1;
  int q0 = qt * 128 + w * 16;
  int keybase = sp * 1024;
  const short* lb = lmat + (size_t)b * 2048 * 512;
  const short* hb = hmat + (size_t)b * 2048 * 512;
  const short* gb = gT + (size_t)b * 512 * 2048;
  short* Op = sp ? OB : OA;
  float2* ml = sp ? mlB : mlA;

  int r0 = lane & 15, g = lane >> 4;

  // Q fragments (B-operand: lane&15 = query col, k-chunk g*8): 64 VGPR
  f16x8 qf[16];
  {
    int q = q0 + r0;
#pragma unroll
    for (int ks = 0; ks < 16; ++ks)
      qf[ks] = *(const f16x8*)&lb[(size_t)q * 512 + ks * 32 + g * 8];
  }
  f32x4 accO[32];  // O^T: query r0, d = nf*16 + g*4 + r
#pragma unroll
  for (int i = 0; i < 32; ++i) accO[i] = (f32x4){0.f, 0.f, 0.f, 0.f};
  float mrun = -3e38f, lsumL = 0.f;

  // K: 2 gload16/wave/tile, linear dest, source col inverse-XOR-swizzled.
  auto stageK = [&](int t) {
    int key0 = keybase + t * 16;
    short* kd = &kbuf[t % 3][0];
#pragma unroll
    for (int j = 0; j < 2; ++j) {
      int wl = w * 2 + j;  // key row 0..15
      gload16(hb + (size_t)(key0 + wl) * 512 + (((lane * 16) ^ ((wl & 7) << 4)) >> 1),
              kd + wl * 512);
    }
  };
  // G: 2 gload16/wave/tile; phys 16B-half = logical ^ ((c>>2)&1).
  auto stageG = [&](int t) {
    int key0 = keybase + t * 16;
    short* gd = &gbuf[t & 1][0];
#pragma unroll
    for (int j = 0; j < 2; ++j) {
      int wl = w * 2 + j;               // 0..15, each covers 32 c-rows
      int c = wl * 32 + (lane >> 1);    // c row 0..511
      int half = (lane & 1) ^ ((lane >> 3) & 1);  // (c>>2)&1 = (lane>>3)&1
      gload16(gb + (size_t)c * 2048 + key0 + half * 8, gd + wl * 512);
    }
  };
  auto QK = [&](int t, f32x4& o) {
    const short* kb = &kbuf[t % 3][0];
#pragma unroll
    for (int ks = 0; ks < 16; ++ks) {
      f16x8 kf = *(const f16x8*)&kb[(r0 * 512 + ks * 32 + g * 8) ^ ((r0 & 7) << 3)];
      o = MFMA(kf, qf[ks], o);
    }
  };

  // prologue: K0,K1 (must drain) then G0 (drain) then K2 (may fly)
  stageK(0); stageK(1); stageG(0); stageK(2);
  BAR_KEEP2();                       // drains K0,K1,G0; K2 in flight
  f32x4 sc = {0.f, 0.f, 0.f, 0.f};
  QK(0, sc);
  BAR_KEEP2();                       // all waves done reading kbuf[0]

  // hoisted swizzled PV base offset (shorts): row r0, phys half g>>1 ^ (r0>>2)&1
  int goff = r0 * 16 + (((g >> 1) ^ ((r0 >> 2) & 1)) << 3) + ((g & 1) << 2);

  for (int t = 0; t < 64; ++t) {
    // issue order matters for counted vmcnt: G first, K last (newest)
    if (t < 63) stageG(t + 1);
    if (t < 61) stageK(t + 3);

    f32x4 sn = {0.f, 0.f, 0.f, 0.f};
    if (t < 63) {
      __builtin_amdgcn_s_setprio(1);
      QK(t + 1, sn);
      __builtin_amdgcn_s_setprio(0);
    }

    // ---- softmax(t): 4 scores/lane (keys g*4+r), lane-local + 2 shuffles ----
    float m2 = fmaxf(fmaxf(sc[0], sc[1]), fmaxf(sc[2], sc[3]));
    m2 = fmaxf(m2, __shfl_xor(m2, 16));
    m2 = fmaxf(m2, __shfl_xor(m2, 32));
    bool ok = (m2 <= mrun + 8.0f);  // defer-max THR=8
    if (!__all((int)ok)) {
      float mnew = fmaxf(mrun, m2);
      float s = __expf(mrun - mnew);
      mrun = mnew;
      lsumL *= s;
#pragma unroll
      for (int nf = 0; nf < 32; ++nf) accO[nf] *= s;
    }
    float p0 = __expf(sc[0] - mrun), p1 = __expf(sc[1] - mrun);
    float p2 = __expf(sc[2] - mrun), p3 = __expf(sc[3] - mrun);
    lsumL += (p0 + p1) + (p2 + p3);

    // P-fragment: 16x16x16 B-operand k-slots (g*4+j) == QK C rows. No shuffles.
    u32x2 pw = {pk2h(p0, p1), pk2h(p2, p3)};
    f16x4 pfrag = __builtin_bit_cast(f16x4, pw);

    // ---- PV(t): O^T += G-frag x P-frag (k=16), 2-way (free) b64 reads ----
    const short* gp = &gbuf[t & 1][goff];
    __builtin_amdgcn_s_setprio(1);
#pragma unroll
    for (int nf = 0; nf < 32; ++nf) {
      f16x4 gf = *(const f16x4*)&gp[nf * 256];
      accO[nf] = MFMA16(gf, pfrag, accO[nf]);
    }
    __builtin_amdgcn_s_setprio(0);

    // counted-vmcnt barrier: own K(t+3) may stay in flight
    if (t < 61) BAR_KEEP2(); else BAR_ALL();
    sc = sn;
  }

  // ---- epilogue: store normalized O (fp16) + (m, l) sidecar ----
  float ls = lsumL;
  ls += __shfl_xor(ls, 16);
  ls += __shfl_xor(ls, 32);
  float inv = 1.0f / ls;
  int q = q0 + r0;
#pragma unroll
  for (int nf = 0; nf < 32; ++nf) {
    s16x4 o;
    o[0] = f2h(accO[nf][0] * inv);
    o[1] = f2h(accO[nf][1] * inv);
    o[2] = f2h(accO[nf][2] * inv);
    o[3] = f2h(accO[nf][3] * inv);
    *(s16x4*)&Op[((size_t)b * 2048 + q) * 512 + nf * 16 + g * 4] = o;
  }
  if (g == 0) ml[(size_t)b * 2048 + q] = make_float2(mrun, ls);
}

// ---------------- fused combine + final GEMM ----------------

__global__ __launch_bounds__(256) void final_gemm_kernel(
    const short* __restrict__ OA, const short* __restrict__ OB,
    const float2* __restrict__ mlA, const float2* __restrict__ mlB,
    const float* __restrict__ x, const short* __restrict__ Wt,
    const float* __restrict__ bias, float* __restrict__ out) {
  __shared__ __align__(16) short lds_a[64 * 40];
  __shared__ __align__(16) short lds_b[512 * 40];
  int tid = threadIdx.x, lane = tid & 63, w = tid >> 6;
  int bm = blockIdx.x * 64;

  int arow = tid >> 2, ac8 = (tid & 3) * 8;
  int grow = bm + arow;
  float2 a2 = mlA[grow], b2 = mlB[grow];
  float ms = fmaxf(a2.x, b2.x);
  float wA = __expf(a2.x - ms) * a2.y;
  float wB = __expf(b2.x - ms) * b2.y;
  float winv = 1.0f / (wA + wB);
  wA *= winv; wB *= winv;

  f32x4 acc[32];
#pragma unroll
  for (int i = 0; i < 32; ++i) acc[i] = (f32x4){0.f, 0.f, 0.f, 0.f};

  for (int k0 = 0; k0 < 512; k0 += 32) {
    {
      size_t base = (size_t)grow * 512 + k0 + ac8;
      f16x8 oa = *(const f16x8*)&OA[base];
      f16x8 ob = *(const f16x8*)&OB[base];
      float4 x0 = *(const float4*)&x[base];
      float4 x1 = *(const float4*)&x[base + 4];
      s16x8 av;
      av[0] = f2h((float)oa[0] * wA + (float)ob[0] * wB + x0.x);
      av[1] = f2h((float)oa[1] * wA + (float)ob[1] * wB + x0.y);
      av[2] = f2h((float)oa[2] * wA + (float)ob[2] * wB + x0.z);
      av[3] = f2h((float)oa[3] * wA + (float)ob[3] * wB + x0.w);
      av[4] = f2h((float)oa[4] * wA + (float)ob[4] * wB + x1.x);
      av[5] = f2h((float)oa[5] * wA + (float)ob[5] * wB + x1.y);
      av[6] = f2h((float)oa[6] * wA + (float)ob[6] * wB + x1.z);
      av[7] = f2h((float)oa[7] * wA + (float)ob[7] * wB + x1.w);
      *(s16x8*)&lds_a[arow * 40 + ac8] = av;
    }
#pragma unroll
    for (int it = 0; it < 8; ++it) {
      int chunk = tid + it * 256;
      int row = chunk >> 2, c8 = (chunk & 3) * 8;
      *(s16x8*)&lds_b[row * 40 + c8] =
          *(const s16x8*)&Wt[(size_t)row * 512 + k0 + c8];
    }
    __syncthreads();
    f16x8 af = *(const f16x8*)&lds_a[(w * 16 + (lane & 15)) * 40 + (lane >> 4) * 8];
#pragma unroll
    for (int nf = 0; nf < 32; ++nf) {
      f16x8 bf = *(const f16x8*)&lds_b[(nf * 16 + (lane & 15)) * 40 + (lane >> 4) * 8];
      acc[nf] = MFMA(af, bf, acc[nf]);
    }
    __syncthreads();
  }

#pragma unroll
  for (int nf = 0; nf < 32; ++nf) {
    int col = nf * 16 + (lane & 15);
    float bv = bias[col];
#pragma unroll
    for (int r = 0; r < 4; ++r) {
      int row = bm + w * 16 + (lane >> 4) * 4 + r;
      out[(size_t)row * 512 + col] = fmaxf(acc[nf][r] + bv, 0.0f);
    }
  }
}

// ---------------- host launch ----------------

extern "C" void kernel_launch(void* const* d_in, const int* in_sizes, int n_in,
                              void* d_out, int out_size, void* d_ws, size_t ws_size,
                              hipStream_t stream) {
  const float* x  = (const float*)d_in[0];
  const float* Wh = (const float*)d_in[1];
  const float* bh = (const float*)d_in[2];
  const float* Wl = (const float*)d_in[3];
  const float* bl = (const float*)d_in[4];
  const float* Wg = (const float*)d_in[5];
  const float* bg = (const float*)d_in[6];
  const float* Wm = (const float*)d_in[7];
  const float* bm = (const float*)d_in[8];

  char* ws = (char*)d_ws;
  const size_t SZ = 16777216;
  short*  xb  = (short*)(ws + 0 * SZ);   // conv_x out; reused as OA by attn
  short*  h   = (short*)(ws + 1 * SZ);
  short*  l   = (short*)(ws + 2 * SZ);
  short*  gT  = (short*)(ws + 3 * SZ);
  short*  OB  = (short*)(ws + 4 * SZ);
  short*  Wt  = (short*)(ws + 5 * SZ);   // 2 MB
  float2* mlA = (float2*)(ws + 5 * SZ + 2097152);            // 128 KB
  float2* mlB = (float2*)(ws + 5 * SZ + 2097152 + 131072);   // 128 KB

  conv_x_kernel<<<4096, 256, 0, stream>>>(x, xb);
  conv_w_kernel<<<4096, 256, 0, stream>>>(Wh, Wl, Wg, Wm, Wt);
  mlp3_kernel<<<dim3(128, 4, 3), 256, 0, stream>>>(xb, Wt, bh, bl, bg, h, l, gT);
  attn_split_kernel<<<256, 512, 0, stream>>>(l, h, gT, xb, OB, mlA, mlB);
  final_gemm_kernel<<<256, 256, 0, stream>>>(xb, OB, mlA, mlB, x,
                                             Wt + 3 * 262144, bm, (float*)d_out);
}

// Round 13
// 231.497 us; speedup vs baseline: 1.4917x; 1.0163x over previous
//
#include <hip/hip_runtime.h>

// B=8, N=2048, C=512. Flash attention + fp16 MFMA pipeline.
// r13: attn = r12 winner (unchanged). mlp3 + final_gemm upgraded to the
// r12-proven pipeline: gload16 staging, triple-buffered [128][32] slices with
// 16B-chunk XOR swizzle ((row>>1)&3), stage(t+2), counted-vmcnt raw barriers
// (1 barrier/k-step). final_gemm keeps fused split-K combine (A reg-staged).
// ws: [0]=xb->OA [1]=h [2]=l [3]=gT [4]=OB [5]=Wt(2MB)+ml(256KB)

typedef __attribute__((ext_vector_type(4))) float f32x4;
typedef __attribute__((ext_vector_type(8))) short s16x8;      // fp16 bit-patterns
typedef __attribute__((ext_vector_type(4))) short s16x4;
typedef __attribute__((ext_vector_type(8))) _Float16 f16x8;   // MFMA operands
typedef __attribute__((ext_vector_type(4))) _Float16 f16x4;
typedef __attribute__((ext_vector_type(2))) unsigned u32x2;

typedef unsigned int u32;
typedef __attribute__((address_space(1))) const u32 gu32;
typedef __attribute__((address_space(3))) u32 lu32;

__device__ __forceinline__ void gload16(const short* g, short* l) {
  __builtin_amdgcn_global_load_lds((gu32*)g, (lu32*)l, 16, 0, 0);
}

__device__ __forceinline__ short f2h(float f) {
  _Float16 h = (_Float16)f;
  return __builtin_bit_cast(short, h);
}

__device__ __forceinline__ unsigned pk2h(float a, float b) {
  return __builtin_bit_cast(unsigned, __builtin_amdgcn_cvt_pkrtz(a, b));
}

#define MFMA(a, b, c) __builtin_amdgcn_mfma_f32_16x16x32_f16(a, b, c, 0, 0, 0)
#define MFMA16(a, b, c) __builtin_amdgcn_mfma_f32_16x16x16f16(a, b, c, 0, 0, 0)

#define BAR_KEEP2()                                          \
  do {                                                       \
    asm volatile("s_waitcnt vmcnt(2)" ::: "memory");         \
    __builtin_amdgcn_s_barrier();                            \
    __builtin_amdgcn_sched_barrier(0);                       \
  } while (0)
#define BAR_KEEP4()                                          \
  do {                                                       \
    asm volatile("s_waitcnt vmcnt(4)" ::: "memory");         \
    __builtin_amdgcn_s_barrier();                            \
    __builtin_amdgcn_sched_barrier(0);                       \
  } while (0)
#define BAR_KEEP4_L()                                        \
  do {                                                       \
    asm volatile("s_waitcnt vmcnt(4) lgkmcnt(0)" ::: "memory"); \
    __builtin_amdgcn_s_barrier();                            \
    __builtin_amdgcn_sched_barrier(0);                       \
  } while (0)
#define BAR_ALL()                                            \
  do {                                                       \
    asm volatile("s_waitcnt vmcnt(0) lgkmcnt(0)" ::: "memory"); \
    __builtin_amdgcn_s_barrier();                            \
    __builtin_amdgcn_sched_barrier(0);                       \
  } while (0)

// ---------------- conversion kernels ----------------

__global__ __launch_bounds__(256) void conv_x_kernel(const float* __restrict__ x,
                                                     short* __restrict__ xb) {
  int i = blockIdx.x * 256 + threadIdx.x;
  const float4* xv = (const float4*)x;
  float4 a = xv[2 * i], b = xv[2 * i + 1];
  s16x8 o;
  o[0] = f2h(a.x); o[1] = f2h(a.y); o[2] = f2h(a.z); o[3] = f2h(a.w);
  o[4] = f2h(b.x); o[5] = f2h(b.y); o[6] = f2h(b.z); o[7] = f2h(b.w);
  ((s16x8*)xb)[i] = o;
}

__global__ __launch_bounds__(256) void conv_w_kernel(const float* __restrict__ Wh,
                                                     const float* __restrict__ Wl,
                                                     const float* __restrict__ Wg,
                                                     const float* __restrict__ Wm,
                                                     short* __restrict__ Wt) {
  int idx = blockIdx.x * 256 + threadIdx.x;
  int k = idx & 511, n = (idx >> 9) & 511, w = idx >> 18;
  const float* W = (w == 0) ? Wh : (w == 1) ? Wl : (w == 2) ? Wg : Wm;
  Wt[idx] = f2h(W[k * 512 + n]);
}

// ---------------- fused 3-way MLP GEMM (pipelined) ----------------
// grid (128,4,3), 256 threads, 4 waves 2x2. Slices [128][32] fp16, 16B-chunk
// XOR swizzle on (row>>1)&3. stage(t+2), vmcnt(4) barriers, 16 k-steps.

__global__ __launch_bounds__(256) void mlp3_kernel(const short* __restrict__ A,
                                                   const short* __restrict__ Wt_all,
                                                   const float* __restrict__ bh,
                                                   const float* __restrict__ bl,
                                                   const float* __restrict__ bg,
                                                   short* __restrict__ h,
                                                   short* __restrict__ l,
                                                   short* __restrict__ gT) {
  int z = blockIdx.z;
  const short* Wt = Wt_all + z * 262144;
  const float* bias = (z == 0) ? bh : (z == 1) ? bl : bg;

  __shared__ __align__(16) short abuf[3][4096];
  __shared__ __align__(16) short bbuf[3][4096];
  int tid = threadIdx.x, lane = tid & 63, w = tid >> 6;
  int wm = w >> 1, wn = w & 1;
  int bm = blockIdx.x * 128, bn = blockIdx.y * 128;
  int rx = lane & 15, g = lane >> 4;

  // stage: 2 A + 2 B gload16 per wave; dest linear, source chunk XOR'd.
  auto stage = [&](int t) {
    int k0 = t * 32;
    short* ad = &abuf[t % 3][0];
    short* bd = &bbuf[t % 3][0];
    int srow = lane >> 2;
    int scol = ((lane & 3) ^ ((lane >> 3) & 3)) * 8;
#pragma unroll
    for (int j = 0; j < 2; ++j) {
      int wl = w * 2 + j;
      int row = wl * 16 + srow;
      gload16(A + (size_t)(bm + row) * 512 + k0 + scol, ad + wl * 512 + lane * 8);
      gload16(Wt + (size_t)(bn + row) * 512 + k0 + scol, bd + wl * 512 + lane * 8);
    }
  };

  f32x4 acc[4][4];
#pragma unroll
  for (int mi = 0; mi < 4; ++mi)
#pragma unroll
    for (int ni = 0; ni < 4; ++ni) acc[mi][ni] = (f32x4){0.f, 0.f, 0.f, 0.f};

  stage(0); stage(1);
  BAR_KEEP4();  // drains stage(0), keeps stage(1)

  int foff = rx * 32 + ((g ^ ((rx >> 1) & 3)) << 3);  // swizzled frag offset

  for (int t = 0; t < 16; ++t) {
    if (t < 14) stage(t + 2);
    const short* ab = &abuf[t % 3][0];
    const short* bb = &bbuf[t % 3][0];
    f16x8 af[4], bfr[4];
#pragma unroll
    for (int mi = 0; mi < 4; ++mi)
      af[mi] = *(const f16x8*)&ab[(wm * 64 + mi * 16) * 32 + foff];
#pragma unroll
    for (int ni = 0; ni < 4; ++ni)
      bfr[ni] = *(const f16x8*)&bb[(wn * 64 + ni * 16) * 32 + foff];
#pragma unroll
    for (int mi = 0; mi < 4; ++mi)
#pragma unroll
      for (int ni = 0; ni < 4; ++ni) acc[mi][ni] = MFMA(af[mi], bfr[ni], acc[mi][ni]);
    if (t < 14) BAR_KEEP4();
    else if (t == 14) BAR_ALL();
  }

#pragma unroll
  for (int mi = 0; mi < 4; ++mi)
#pragma unroll
    for (int ni = 0; ni < 4; ++ni) {
      int col = bn + wn * 64 + ni * 16 + rx;
      float bv = bias[col];
#pragma unroll
      for (int r = 0; r < 4; ++r) {
        int row = bm + wm * 64 + mi * 16 + g * 4 + r;
        float v = fmaxf(acc[mi][ni][r] + bv, 0.0f);
        short o = f2h(v);
        if (z == 0) h[(size_t)row * 512 + col] = o;
        else if (z == 1) l[(size_t)row * 512 + col] = o;
        else {
          int bb2 = row >> 11, mm = row & 2047;
          gT[((size_t)bb2 * 512 + col) * 2048 + mm] = o;
        }
      }
    }
}

// ---------------- flash attention, split-K (r12, unchanged) ----------------

__global__ __launch_bounds__(512, 1) void attn_split_kernel(
    const short* __restrict__ lmat, const short* __restrict__ hmat,
    const short* __restrict__ gT,
    short* __restrict__ OA, short* __restrict__ OB,
    float2* __restrict__ mlA, float2* __restrict__ mlB) {
  __shared__ __align__(16) short kbuf[3][8192];  // 48KB
  __shared__ __align__(16) short gbuf[2][8192];  // 32KB
  int tid = threadIdx.x, lane = tid & 63, w = tid >> 6;  // w in 0..7
  int b = blockIdx.x & 7;
  int idx = blockIdx.x >> 3;
  int qt = idx >> 1, sp = idx & 1;
  int q0 = qt * 128 + w * 16;
  int keybase = sp * 1024;
  const short* lb = lmat + (size_t)b * 2048 * 512;
  const short* hb = hmat + (size_t)b * 2048 * 512;
  const short* gb = gT + (size_t)b * 512 * 2048;
  short* Op = sp ? OB : OA;
  float2* ml = sp ? mlB : mlA;

  int r0 = lane & 15, g = lane >> 4;

  f16x8 qf[16];
  {
    int q = q0 + r0;
#pragma unroll
    for (int ks = 0; ks < 16; ++ks)
      qf[ks] = *(const f16x8*)&lb[(size_t)q * 512 + ks * 32 + g * 8];
  }
  f32x4 accO[32];
#pragma unroll
  for (int i = 0; i < 32; ++i) accO[i] = (f32x4){0.f, 0.f, 0.f, 0.f};
  float mrun = -3e38f, lsumL = 0.f;

  auto stageK = [&](int t) {
    int key0 = keybase + t * 16;
    short* kd = &kbuf[t % 3][0];
#pragma unroll
    for (int j = 0; j < 2; ++j) {
      int wl = w * 2 + j;
      gload16(hb + (size_t)(key0 + wl) * 512 + (((lane * 16) ^ ((wl & 7) << 4)) >> 1),
              kd + wl * 512);
    }
  };
  auto stageG = [&](int t) {
    int key0 = keybase + t * 16;
    short* gd = &gbuf[t & 1][0];
#pragma unroll
    for (int j = 0; j < 2; ++j) {
      int wl = w * 2 + j;
      int c = wl * 32 + (lane >> 1);
      int half = (lane & 1) ^ ((lane >> 3) & 1);
      gload16(gb + (size_t)c * 2048 + key0 + half * 8, gd + wl * 512);
    }
  };
  auto QK = [&](int t, f32x4& o) {
    const short* kb = &kbuf[t % 3][0];
#pragma unroll
    for (int ks = 0; ks < 16; ++ks) {
      f16x8 kf = *(const f16x8*)&kb[(r0 * 512 + ks * 32 + g * 8) ^ ((r0 & 7) << 3)];
      o = MFMA(kf, qf[ks], o);
    }
  };

  stageK(0); stageK(1); stageG(0); stageK(2);
  BAR_KEEP2();
  f32x4 sc = {0.f, 0.f, 0.f, 0.f};
  QK(0, sc);
  BAR_KEEP2();

  int goff = r0 * 16 + (((g >> 1) ^ ((r0 >> 2) & 1)) << 3) + ((g & 1) << 2);

  for (int t = 0; t < 64; ++t) {
    if (t < 63) stageG(t + 1);
    if (t < 61) stageK(t + 3);

    f32x4 sn = {0.f, 0.f, 0.f, 0.f};
    if (t < 63) {
      __builtin_amdgcn_s_setprio(1);
      QK(t + 1, sn);
      __builtin_amdgcn_s_setprio(0);
    }

    float m2 = fmaxf(fmaxf(sc[0], sc[1]), fmaxf(sc[2], sc[3]));
    m2 = fmaxf(m2, __shfl_xor(m2, 16));
    m2 = fmaxf(m2, __shfl_xor(m2, 32));
    bool ok = (m2 <= mrun + 8.0f);
    if (!__all((int)ok)) {
      float mnew = fmaxf(mrun, m2);
      float s = __expf(mrun - mnew);
      mrun = mnew;
      lsumL *= s;
#pragma unroll
      for (int nf = 0; nf < 32; ++nf) accO[nf] *= s;
    }
    float p0 = __expf(sc[0] - mrun), p1 = __expf(sc[1] - mrun);
    float p2 = __expf(sc[2] - mrun), p3 = __expf(sc[3] - mrun);
    lsumL += (p0 + p1) + (p2 + p3);

    u32x2 pw = {pk2h(p0, p1), pk2h(p2, p3)};
    f16x4 pfrag = __builtin_bit_cast(f16x4, pw);

    const short* gp = &gbuf[t & 1][goff];
    __builtin_amdgcn_s_setprio(1);
#pragma unroll
    for (int nf = 0; nf < 32; ++nf) {
      f16x4 gf = *(const f16x4*)&gp[nf * 256];
      accO[nf] = MFMA16(gf, pfrag, accO[nf]);
    }
    __builtin_amdgcn_s_setprio(0);

    if (t < 61) BAR_KEEP2();
    else {
      asm volatile("s_waitcnt vmcnt(0)" ::: "memory");
      __builtin_amdgcn_s_barrier();
      __builtin_amdgcn_sched_barrier(0);
    }
    sc = sn;
  }

  float ls = lsumL;
  ls += __shfl_xor(ls, 16);
  ls += __shfl_xor(ls, 32);
  float inv = 1.0f / ls;
  int q = q0 + r0;
#pragma unroll
  for (int nf = 0; nf < 32; ++nf) {
    s16x4 o;
    o[0] = f2h(accO[nf][0] * inv);
    o[1] = f2h(accO[nf][1] * inv);
    o[2] = f2h(accO[nf][2] * inv);
    o[3] = f2h(accO[nf][3] * inv);
    *(s16x4*)&Op[((size_t)b * 2048 + q) * 512 + nf * 16 + g * 4] = o;
  }
  if (g == 0) ml[(size_t)b * 2048 + q] = make_float2(mrun, ls);
}

// ---------------- fused combine + final GEMM (pipelined 128x128) ----------------
// grid (128,4). A reg-staged (combine+residual fused, dbuf, swizzled ds_write);
// B via gload16 triple-buffer. Barrier = vmcnt(4) lgkmcnt(0).

__global__ __launch_bounds__(256) void final_gemm_kernel(
    const short* __restrict__ OA, const short* __restrict__ OB,
    const float2* __restrict__ mlA, const float2* __restrict__ mlB,
    const float* __restrict__ x, const short* __restrict__ Wt,
    const float* __restrict__ bias, float* __restrict__ out) {
  __shared__ __align__(16) short abuf[2][4096];
  __shared__ __align__(16) short bbuf[3][4096];
  int tid = threadIdx.x, lane = tid & 63, w = tid >> 6;
  int wm = w >> 1, wn = w & 1;
  int bm = blockIdx.x * 128, bn = blockIdx.y * 128;
  int rx = lane & 15, g = lane >> 4;

  // per-thread combine weights for its two fixed A rows (row0 = tid>>2, +64)
  float wgt[2][2];
#pragma unroll
  for (int it = 0; it < 2; ++it) {
    int row = (tid >> 2) + it * 64;
    float2 a2 = mlA[bm + row], b2 = mlB[bm + row];
    float ms = fmaxf(a2.x, b2.x);
    float wA = __expf(a2.x - ms) * a2.y;
    float wB = __expf(b2.x - ms) * b2.y;
    float winv = 1.0f / (wA + wB);
    wgt[it][0] = wA * winv;
    wgt[it][1] = wB * winv;
  }

  auto stageB = [&](int t) {
    int k0 = t * 32;
    short* bd = &bbuf[t % 3][0];
    int srow = lane >> 2;
    int scol = ((lane & 3) ^ ((lane >> 3) & 3)) * 8;
#pragma unroll
    for (int j = 0; j < 2; ++j) {
      int wl = w * 2 + j;
      int row = wl * 16 + srow;
      gload16(Wt + (size_t)(bn + row) * 512 + k0 + scol, bd + wl * 512 + lane * 8);
    }
  };
  // A: load + combine + residual -> regs (issued early), written late
  auto loadA = [&](int t, s16x8 av[2]) {
#pragma unroll
    for (int it = 0; it < 2; ++it) {
      int c = tid + it * 256;
      int row = c >> 2, col8 = (c & 3) * 8;
      size_t base = (size_t)(bm + row) * 512 + t * 32 + col8;
      f16x8 oa = *(const f16x8*)&OA[base];
      f16x8 ob = *(const f16x8*)&OB[base];
      float4 x0 = *(const float4*)&x[base];
      float4 x1 = *(const float4*)&x[base + 4];
      float wA = wgt[it][0], wB = wgt[it][1];
      s16x8 v;
      v[0] = f2h((float)oa[0] * wA + (float)ob[0] * wB + x0.x);
      v[1] = f2h((float)oa[1] * wA + (float)ob[1] * wB + x0.y);
      v[2] = f2h((float)oa[2] * wA + (float)ob[2] * wB + x0.z);
      v[3] = f2h((float)oa[3] * wA + (float)ob[3] * wB + x0.w);
      v[4] = f2h((float)oa[4] * wA + (float)ob[4] * wB + x1.x);
      v[5] = f2h((float)oa[5] * wA + (float)ob[5] * wB + x1.y);
      v[6] = f2h((float)oa[6] * wA + (float)ob[6] * wB + x1.z);
      v[7] = f2h((float)oa[7] * wA + (float)ob[7] * wB + x1.w);
      av[it] = v;
    }
  };
  auto writeA = [&](int t, s16x8 av[2]) {
    short* ad = &abuf[t & 1][0];
#pragma unroll
    for (int it = 0; it < 2; ++it) {
      int c = tid + it * 256;
      int row = c >> 2;
      int chunk_p = (c & 3) ^ ((row >> 1) & 3);
      *(s16x8*)&ad[row * 32 + chunk_p * 8] = av[it];
    }
  };

  f32x4 acc[4][4];
#pragma unroll
  for (int mi = 0; mi < 4; ++mi)
#pragma unroll
    for (int ni = 0; ni < 4; ++ni) acc[mi][ni] = (f32x4){0.f, 0.f, 0.f, 0.f};

  // prologue
  s16x8 av[2];
  loadA(0, av);
  stageB(0); stageB(1);
  writeA(0, av);
  BAR_KEEP4_L();  // drains B(0)+A writes, keeps B(1)

  int foff = rx * 32 + ((g ^ ((rx >> 1) & 3)) << 3);

  for (int t = 0; t < 16; ++t) {
    if (t < 15) loadA(t + 1, av);   // issue A global loads early
    if (t < 14) stageB(t + 2);
    const short* ab = &abuf[t & 1][0];
    const short* bb = &bbuf[t % 3][0];
    f16x8 af[4], bfr[4];
#pragma unroll
    for (int mi = 0; mi < 4; ++mi)
      af[mi] = *(const f16x8*)&ab[(wm * 64 + mi * 16) * 32 + foff];
#pragma unroll
    for (int ni = 0; ni < 4; ++ni)
      bfr[ni] = *(const f16x8*)&bb[(wn * 64 + ni * 16) * 32 + foff];
#pragma unroll
    for (int mi = 0; mi < 4; ++mi)
#pragma unroll
      for (int ni = 0; ni < 4; ++ni) acc[mi][ni] = MFMA(af[mi], bfr[ni], acc[mi][ni]);
    if (t < 15) writeA(t + 1, av);  // cvt+ds_write after compute
    if (t < 14) BAR_KEEP4_L();
    else if (t == 14) BAR_ALL();
  }

#pragma unroll
  for (int mi = 0; mi < 4; ++mi)
#pragma unroll
    for (int ni = 0; ni < 4; ++ni) {
      int col = bn + wn * 64 + ni * 16 + rx;
      float bv = bias[col];
#pragma unroll
      for (int r = 0; r < 4; ++r) {
        int row = bm + wm * 64 + mi * 16 + g * 4 + r;
        out[(size_t)row * 512 + col] = fmaxf(acc[mi][ni][r] + bv, 0.0f);
      }
    }
}

// ---------------- host launch ----------------

extern "C" void kernel_launch(void* const* d_in, const int* in_sizes, int n_in,
                              void* d_out, int out_size, void* d_ws, size_t ws_size,
                              hipStream_t stream) {
  const float* x  = (const float*)d_in[0];
  const float* Wh = (const float*)d_in[1];
  const float* bh = (const float*)d_in[2];
  const float* Wl = (const float*)d_in[3];
  const float* bl = (const float*)d_in[4];
  const float* Wg = (const float*)d_in[5];
  const float* bg = (const float*)d_in[6];
  const float* Wm = (const float*)d_in[7];
  const float* bm = (const float*)d_in[8];

  char* ws = (char*)d_ws;
  const size_t SZ = 16777216;
  short*  xb  = (short*)(ws + 0 * SZ);   // conv_x out; reused as OA by attn
  short*  h   = (short*)(ws + 1 * SZ);
  short*  l   = (short*)(ws + 2 * SZ);
  short*  gT  = (short*)(ws + 3 * SZ);
  short*  OB  = (short*)(ws + 4 * SZ);
  short*  Wt  = (short*)(ws + 5 * SZ);   // 2 MB
  float2* mlA = (float2*)(ws + 5 * SZ + 2097152);            // 128 KB
  float2* mlB = (float2*)(ws + 5 * SZ + 2097152 + 131072);   // 128 KB

  conv_x_kernel<<<4096, 256, 0, stream>>>(x, xb);
  conv_w_kernel<<<4096, 256, 0, stream>>>(Wh, Wl, Wg, Wm, Wt);
  mlp3_kernel<<<dim3(128, 4, 3), 256, 0, stream>>>(xb, Wt, bh, bl, bg, h, l, gT);
  attn_split_kernel<<<256, 512, 0, stream>>>(l, h, gT, xb, OB, mlA, mlB);
  final_gemm_kernel<<<dim3(128, 4), 256, 0, stream>>>(xb, OB, mlA, mlB, x,
                                                      Wt + 3 * 262144, bm,
                                                      (float*)d_out);
}